// Round 4
// baseline (7924.358 us; speedup 1.0000x reference)
//
#include <hip/hip_runtime.h>
#include <hip/hip_bf16.h>

// ---------------------------------------------------------------------------
// AttentionHeteroConv. R4: conflict-free LDS layouts everywhere.
// B matrices live in LDS as float4 k-chunks: Bs4[k4][n], row stride odd ->
// staging is float4->float4 (no scalar transpose), GEMM B-reads are
// lane-consecutive b128. Thread n-columns interleaved (n = tn + 32*j).
// ---------------------------------------------------------------------------

#define C 128
#define NHEAD 4
#define DH 32
#define QK_SCALE 0.17677669529663687f  // 1/sqrt(32)

// ---------------------------------------------------------------------------
// K2: transform: h = x@Wnb^T + bnb ; self = x@Wself^T + bself
// M=32 rows/block, N=256 (0-127 Wnb, 128-255 Wself), K=128.
// ---------------------------------------------------------------------------
__global__ __launch_bounds__(256, 3) void transform_kernel(
    const float* __restrict__ x, int n_rows,
    const float* __restrict__ Wnb, const float* __restrict__ bnb,
    const float* __restrict__ Wself, const float* __restrict__ bself,
    float* __restrict__ h, float* __restrict__ selfout)
{
    __shared__ float As[32 * 132];
    __shared__ float4 Bs4[8 * 257];
    __shared__ float biasS[256];

    const int tid = threadIdx.x;
    const int row0 = blockIdx.x * 32;

    if (tid < 128) biasS[tid] = bnb[tid];
    else           biasS[tid] = bself[tid - 128];

#pragma unroll
    for (int i = 0; i < 4; i++) {
        int id = tid + i * 256;              // 1024 = 32 rows x 32 f4
        int r = id >> 5, c4 = id & 31;
        float4 v = make_float4(0.f, 0.f, 0.f, 0.f);
        if (row0 + r < n_rows) v = ((const float4*)x)[(size_t)(row0 + r) * 32 + c4];
        *(float4*)&As[r * 132 + c4 * 4] = v;
    }

    const int tn = tid & 31;
    const int tm = tid >> 5;
    float acc[4][8];
#pragma unroll
    for (int m = 0; m < 4; m++)
#pragma unroll
        for (int j = 0; j < 8; j++) acc[m][j] = 0.f;

    const float4* Wnb4 = (const float4*)Wnb;
    const float4* Wsf4 = (const float4*)Wself;

    for (int ks = 0; ks < 4; ks++) {
        __syncthreads();
#pragma unroll
        for (int i = 0; i < 8; i++) {
            int id = tid + i * 256;          // 2048 = 256 n x 8 k4
            int n = id >> 3, k4 = id & 7;
            const float4* Wp = (i < 4) ? Wnb4 : Wsf4;
            Bs4[k4 * 257 + n] = Wp[(size_t)(n & 127) * 32 + ks * 8 + k4];
        }
        __syncthreads();
#pragma unroll
        for (int k4 = 0; k4 < 8; k4++) {
            float4 a[4];
#pragma unroll
            for (int m = 0; m < 4; m++)
                a[m] = *(const float4*)&As[(tm * 4 + m) * 132 + ks * 32 + k4 * 4];
#pragma unroll
            for (int j = 0; j < 8; j++) {
                float4 b = Bs4[k4 * 257 + tn + 32 * j];
#pragma unroll
                for (int m = 0; m < 4; m++)
                    acc[m][j] += a[m].x * b.x + a[m].y * b.y
                               + a[m].z * b.z + a[m].w * b.w;
            }
        }
    }

#pragma unroll
    for (int m = 0; m < 4; m++) {
        int row = row0 + tm * 4 + m;
        if (row < n_rows) {
#pragma unroll
            for (int j = 0; j < 8; j++) {
                int col = tn + 32 * j;
                float v = acc[m][j] + biasS[col];
                if (j < 4) h[(size_t)row * C + col] = v;
                else       selfout[(size_t)row * C + col - 128] = v;
            }
        }
    }
}

// ---------------------------------------------------------------------------
// CSR build: zero + histogram + exclusive-scan (single block) + fill.
// ---------------------------------------------------------------------------
__global__ __launch_bounds__(256) void zero_kernel(int* __restrict__ p, int n)
{
    int i = blockIdx.x * 256 + threadIdx.x;
    if (i < n) p[i] = 0;
}

__global__ __launch_bounds__(256) void hist_kernel(
    const int* __restrict__ dst, int n, int* __restrict__ cur)
{
    int i = blockIdx.x * 256 + threadIdx.x;
    if (i < n) atomicAdd(&cur[dst[i]], 1);
}

__global__ __launch_bounds__(1024) void scan_kernel(int* __restrict__ cur, int n)
{
    __shared__ int wsum[16];
    __shared__ int carryS;
    const int tid = threadIdx.x, lane = tid & 63, wv = tid >> 6;
    if (tid == 0) carryS = 0;
    __syncthreads();
    for (int base = 0; base < n; base += 1024) {
        int i = base + tid;
        int v = (i < n) ? cur[i] : 0;
        int x = v;
#pragma unroll
        for (int d = 1; d < 64; d <<= 1) {
            int t = __shfl_up(x, d, 64);
            if (lane >= d) x += t;
        }
        if (lane == 63) wsum[wv] = x;
        int carry = carryS;
        __syncthreads();
        int wpre = 0;
#pragma unroll
        for (int w2 = 0; w2 < 16; w2++) wpre += (w2 < wv) ? wsum[w2] : 0;
        int excl = x - v + wpre + carry;
        if (i < n) cur[i] = excl;
        __syncthreads();
        if (tid == 0) {
            int t = 0;
#pragma unroll
            for (int w2 = 0; w2 < 16; w2++) t += wsum[w2];
            carryS = carry + t;
        }
        __syncthreads();
    }
}

__global__ __launch_bounds__(256) void fill_kernel(
    const int* __restrict__ src, const int* __restrict__ dst, int n,
    int* __restrict__ cur, int* __restrict__ csr)
{
    int i = blockIdx.x * 256 + threadIdx.x;
    if (i < n) {
        int p = atomicAdd(&cur[dst[i]], 1);
        csr[p] = src[i];
    }
}

// ---------------------------------------------------------------------------
// K4: fused gather-aggregate + qkv-GEMM + attention, 8 nodes/block.
// LDS region R (floats):
//   GEMM:    As[32][132] @0,  Bs4[8][385] float4 @4224 (k4-chunk layout)
//   overlay: qkv[40][388] @0  (rows node*5+s; q 0-127, k 128-255, v 256-383)
// ---------------------------------------------------------------------------
#define ATN 8
#define AS_F 4224            // As floats
#define RSZ 16544            // As 4224 + Bs 8*385*4 = 12320
#define QROW 388             // overlay row stride (floats)

__global__ __launch_bounds__(256, 2) void attn_fused_kernel(
    const float* __restrict__ h_src, const int* __restrict__ csr,
    const int* __restrict__ cur, const float* __restrict__ selfF,
    const float* __restrict__ Wip, const float* __restrict__ bip,
    float* __restrict__ omean_g, int n_nodes)
{
    __shared__ float R[RSZ];
    __shared__ float attS[ATN * NHEAD * 25];
    __shared__ float bipS[384];
    __shared__ float cinv[ATN];

    const int tid = threadIdx.x;
    const int lane = tid & 63;
    const int wv = tid >> 6;
    const int node0 = blockIdx.x * ATN;

    // ---- P0a: stage bip + self rows (A rows nl*4+0) ----
    for (int i = tid; i < 384; i += 256) bipS[i] = bip[i];
    {
        int r = tid >> 5, c4 = tid & 31;
        int node = node0 + r;
        float4 v = make_float4(0.f, 0.f, 0.f, 0.f);
        if (node < n_nodes) v = ((const float4*)selfF)[(size_t)node * 32 + c4];
        *(float4*)&R[(r * 4 + 0) * 132 + c4 * 4] = v;
    }

    // ---- P0b: gather max/min/sum (A rows nl*4+{1,2,3}), 2 nodes/wave ----
    const float2* h2 = (const float2*)h_src;
#pragma unroll
    for (int half = 0; half < 2; half++) {
        int nl = wv * 2 + half;
        int node = node0 + nl;
        float2 vs = make_float2(0.f, 0.f);
        float2 vmx = make_float2(-3.4e38f, -3.4e38f);
        float2 vmn = make_float2(3.4e38f, 3.4e38f);
        int deg = 0;
        if (node < n_nodes) {
            int start = (node == 0) ? 0 : cur[node - 1];
            int end = cur[node];
            deg = end - start;
            int e = start;
            for (; e + 4 <= end; e += 4) {
                int s0 = csr[e], s1 = csr[e + 1], s2 = csr[e + 2], s3 = csr[e + 3];
                float2 v0 = h2[(size_t)s0 * 64 + lane];
                float2 v1 = h2[(size_t)s1 * 64 + lane];
                float2 v2 = h2[(size_t)s2 * 64 + lane];
                float2 v3 = h2[(size_t)s3 * 64 + lane];
                vs.x += v0.x + v1.x + v2.x + v3.x;
                vs.y += v0.y + v1.y + v2.y + v3.y;
                vmx.x = fmaxf(fmaxf(vmx.x, v0.x), fmaxf(v1.x, fmaxf(v2.x, v3.x)));
                vmx.y = fmaxf(fmaxf(vmx.y, v0.y), fmaxf(v1.y, fmaxf(v2.y, v3.y)));
                vmn.x = fminf(fminf(vmn.x, v0.x), fminf(v1.x, fminf(v2.x, v3.x)));
                vmn.y = fminf(fminf(vmn.y, v0.y), fminf(v1.y, fminf(v2.y, v3.y)));
            }
            for (; e < end; e++) {
                int s0 = csr[e];
                float2 v0 = h2[(size_t)s0 * 64 + lane];
                vs.x += v0.x; vs.y += v0.y;
                vmx.x = fmaxf(vmx.x, v0.x); vmx.y = fmaxf(vmx.y, v0.y);
                vmn.x = fminf(vmn.x, v0.x); vmn.y = fminf(vmn.y, v0.y);
            }
        }
        if (deg == 0) {
            vmx = make_float2(0.f, 0.f);
            vmn = make_float2(0.f, 0.f);
        }
        *(float2*)&R[(nl * 4 + 1) * 132 + 2 * lane] = vmx;
        *(float2*)&R[(nl * 4 + 2) * 132 + 2 * lane] = vmn;
        *(float2*)&R[(nl * 4 + 3) * 132 + 2 * lane] = vs;
        if (lane == 0) cinv[nl] = 1.f / (float)max(deg, 1);
    }

    // ---- P1: GEMM qkv = A @ Wip^T  (M=32, N=384, K=128) ----
    const int tn = tid & 31;
    const int tm = tid >> 5;
    float acc[4][12];
#pragma unroll
    for (int m = 0; m < 4; m++)
#pragma unroll
        for (int j = 0; j < 12; j++) acc[m][j] = 0.f;

    const float4* Wip4 = (const float4*)Wip;
    float4* Bs4 = (float4*)&R[AS_F];

    for (int ks = 0; ks < 4; ks++) {
        __syncthreads();
#pragma unroll
        for (int i = 0; i < 12; i++) {
            int id = tid + i * 256;          // 3072 = 384 n x 8 k4
            int n = id >> 3, k4 = id & 7;
            Bs4[k4 * 385 + n] = Wip4[(size_t)n * 32 + ks * 8 + k4];
        }
        __syncthreads();
#pragma unroll
        for (int k4 = 0; k4 < 8; k4++) {
            float4 a[4];
#pragma unroll
            for (int m = 0; m < 4; m++)
                a[m] = *(const float4*)&R[(tm * 4 + m) * 132 + ks * 32 + k4 * 4];
#pragma unroll
            for (int j = 0; j < 12; j++) {
                float4 b = Bs4[k4 * 385 + tn + 32 * j];
#pragma unroll
                for (int m = 0; m < 4; m++)
                    acc[m][j] += a[m].x * b.x + a[m].y * b.y
                               + a[m].z * b.z + a[m].w * b.w;
            }
        }
    }

    // ---- P2: C-tile (+bias) -> qkv overlay rows node*5+s ----
    __syncthreads();
#pragma unroll
    for (int m = 0; m < 4; m++) {
        int mr = tm * 4 + m;
        int node = mr >> 2, s = mr & 3;
        float* q = &R[(node * 5 + s) * QROW];
#pragma unroll
        for (int j = 0; j < 12; j++) {
            int n = tn + 32 * j;
            q[n] = acc[m][j] + bipS[n];
        }
    }
    __syncthreads();

    // ---- P3: mean rows: (qkv_sum - b)*cinv + b ----
#pragma unroll
    for (int i = 0; i < 12; i++) {
        int id = tid + i * 256;              // 3072 = 8 x 384
        int n = id / 384, c = id - n * 384;
        float b = bipS[c];
        R[(n * 5 + 4) * QROW + c] = (R[(n * 5 + 3) * QROW + c] - b) * cinv[n] + b;
    }
    __syncthreads();

    // ---- P4a: scores, all heads (threads: n,i,j) ----
    if (tid < ATN * 25) {
        int n = tid / 25, r = tid - n * 25, i = r / 5, j = r - (r / 5) * 5;
        const float4* qr = (const float4*)&R[(n * 5 + i) * QROW];
        const float4* kr = (const float4*)&R[(n * 5 + j) * QROW + C];
#pragma unroll
        for (int h = 0; h < NHEAD; h++) {
            float s = 0.f;
#pragma unroll
            for (int d4 = 0; d4 < 8; d4++) {
                float4 q = qr[h * 8 + d4];
                float4 k = kr[h * 8 + d4];
                s += q.x * k.x + q.y * k.y + q.z * k.z + q.w * k.w;
            }
            attS[((n * NHEAD + h) * 5 + i) * 5 + j] = s * QK_SCALE;
        }
    }
    __syncthreads();

    // ---- P4b: softmax rows (threads: n,h,i), fold 1/5 ----
    if (tid < ATN * NHEAD * 5) {
        int n = tid / 20, r = tid - n * 20, h = r / 5, i = r - (r / 5) * 5;
        float* a = &attS[((n * NHEAD + h) * 5 + i) * 5];
        float m = a[0];
#pragma unroll
        for (int j = 1; j < 5; j++) m = fmaxf(m, a[j]);
        float e[5], l = 0.f;
#pragma unroll
        for (int j = 0; j < 5; j++) { e[j] = __expf(a[j] - m); l += e[j]; }
        float inv = 0.2f / l;
#pragma unroll
        for (int j = 0; j < 5; j++) a[j] = e[j] * inv;
    }
    __syncthreads();

    // ---- P4c: PV via column-summed weights -> omean_g directly ----
#pragma unroll
    for (int it = 0; it < 4; it++) {
        int id = tid + it * 256;             // 1024 = 8 n x 128 c
        int n = id >> 7, c = id & 127, h = c >> 5;
        const float* ab = &attS[(n * NHEAD + h) * 25];
        float o = 0.f;
#pragma unroll
        for (int j = 0; j < 5; j++) {
            float wj = ab[0 * 5 + j] + ab[1 * 5 + j] + ab[2 * 5 + j]
                     + ab[3 * 5 + j] + ab[4 * 5 + j];
            o += wj * R[(n * 5 + j) * QROW + 2 * C + c];
        }
        int node = node0 + n;
        if (node < n_nodes) omean_g[(size_t)node * C + c] = o;
    }
}

// ---------------------------------------------------------------------------
// K5: out = self(d_out) + omean @ Wop^T + bop.  M=32/block, N=128, K=128.
// ---------------------------------------------------------------------------
__global__ __launch_bounds__(256, 4) void outproj_kernel(
    const float* __restrict__ omean_g, const float* __restrict__ Wop,
    const float* __restrict__ bop, float* __restrict__ out, int M)
{
    __shared__ float As[32 * 132];
    __shared__ float4 Bs4[8 * 129];
    __shared__ float bopS[C];

    const int tid = threadIdx.x;
    const int m0 = blockIdx.x * 32;

    if (tid < C) bopS[tid] = bop[tid];
#pragma unroll
    for (int i = 0; i < 4; i++) {
        int id = tid + i * 256;
        int r = id >> 5, c4 = id & 31;
        float4 v = make_float4(0.f, 0.f, 0.f, 0.f);
        int m = m0 + r;
        if (m < M) v = ((const float4*)omean_g)[(size_t)m * 32 + c4];
        *(float4*)&As[r * 132 + c4 * 4] = v;
    }

    const int tn = tid & 31;
    const int tm = tid >> 5;
    float acc[4][4];
#pragma unroll
    for (int m = 0; m < 4; m++)
#pragma unroll
        for (int j = 0; j < 4; j++) acc[m][j] = 0.f;

    const float4* Wop4 = (const float4*)Wop;

    for (int ks = 0; ks < 4; ks++) {
        __syncthreads();
#pragma unroll
        for (int i = 0; i < 4; i++) {
            int id = tid + i * 256;          // 1024 = 128 n x 8 k4
            int n = id >> 3, k4 = id & 7;
            Bs4[k4 * 129 + n] = Wop4[(size_t)n * 32 + ks * 8 + k4];
        }
        __syncthreads();
#pragma unroll
        for (int k4 = 0; k4 < 8; k4++) {
            float4 a[4];
#pragma unroll
            for (int m = 0; m < 4; m++)
                a[m] = *(const float4*)&As[(tm * 4 + m) * 132 + ks * 32 + k4 * 4];
#pragma unroll
            for (int j = 0; j < 4; j++) {
                float4 b = Bs4[k4 * 129 + tn + 32 * j];
#pragma unroll
                for (int m = 0; m < 4; m++)
                    acc[m][j] += a[m].x * b.x + a[m].y * b.y
                               + a[m].z * b.z + a[m].w * b.w;
            }
        }
    }

#pragma unroll
    for (int m = 0; m < 4; m++) {
        int row = m0 + tm * 4 + m;
        if (row < M) {
#pragma unroll
            for (int j = 0; j < 4; j++) {
                int col = tn + 32 * j;
                float* p = &out[(size_t)row * C + col];
                *p += acc[m][j] + bopS[col];
            }
        }
    }
}

// ---------------------------------------------------------------------------
extern "C" void kernel_launch(void* const* d_in, const int* in_sizes, int n_in,
                              void* d_out, int out_size, void* d_ws, size_t ws_size,
                              hipStream_t stream) {
    const float* x_user = (const float*)d_in[0];
    const float* x_item = (const float*)d_in[1];
    const int*   ei_u2i = (const int*)d_in[2];
    const int*   ei_i2u = (const int*)d_in[3];
    const float* W_nb   = (const float*)d_in[4];
    const float* b_nb   = (const float*)d_in[5];
    const float* W_self = (const float*)d_in[6];
    const float* b_self = (const float*)d_in[7];
    const float* Wip    = (const float*)d_in[8];
    const float* bip    = (const float*)d_in[9];
    const float* Wop    = (const float*)d_in[10];
    const float* bop    = (const float*)d_in[11];

    const int NU = in_sizes[0] / C;
    const int NI = in_sizes[1] / C;
    const int E1 = in_sizes[2] / 2;
    const int E2 = in_sizes[3] / 2;

    float* out_user = (float*)d_out;
    float* out_item = out_user + (size_t)NU * C;

    // workspace: h (rc) | omean (rc) | cur (maxN ints) | csr (maxE ints)
    float* ws = (float*)d_ws;
    const size_t rc = (size_t)(NU + NI) * C;
    float* h_all     = ws;
    float* omean_all = h_all + rc;
    int*   cur       = (int*)(omean_all + rc);
    const int maxN   = (NU > NI) ? NU : NI;
    int*   csr       = cur + maxN;

    float* h_user = h_all;
    float* h_item = h_all + (size_t)NU * C;
    float* om_user = omean_all;
    float* om_item = omean_all + (size_t)NU * C;

    transform_kernel<<<(NU + 31) / 32, 256, 0, stream>>>(
        x_user, NU, W_nb, b_nb, W_self, b_self, h_user, out_user);
    transform_kernel<<<(NI + 31) / 32, 256, 0, stream>>>(
        x_item, NI, W_nb, b_nb, W_self, b_self, h_item, out_item);

    // direction A: user -> item
    zero_kernel<<<(NI + 255) / 256, 256, 0, stream>>>(cur, NI);
    hist_kernel<<<(E1 + 255) / 256, 256, 0, stream>>>(ei_u2i + E1, E1, cur);
    scan_kernel<<<1, 1024, 0, stream>>>(cur, NI);
    fill_kernel<<<(E1 + 255) / 256, 256, 0, stream>>>(ei_u2i, ei_u2i + E1, E1, cur, csr);
    attn_fused_kernel<<<(NI + ATN - 1) / ATN, 256, 0, stream>>>(
        h_user, csr, cur, out_item, Wip, bip, om_item, NI);

    // direction B: item -> user
    zero_kernel<<<(NU + 255) / 256, 256, 0, stream>>>(cur, NU);
    hist_kernel<<<(E2 + 255) / 256, 256, 0, stream>>>(ei_i2u + E2, E2, cur);
    scan_kernel<<<1, 1024, 0, stream>>>(cur, NU);
    fill_kernel<<<(E2 + 255) / 256, 256, 0, stream>>>(ei_i2u, ei_i2u + E2, E2, cur, csr);
    attn_fused_kernel<<<(NU + ATN - 1) / ATN, 256, 0, stream>>>(
        h_item, csr, cur, out_user, Wip, bip, om_user, NU);

    outproj_kernel<<<(NU + NI + 31) / 32, 256, 0, stream>>>(
        omean_all, Wop, bop, (float*)d_out, NU + NI);
}

// Round 5
// 7505.962 us; speedup vs baseline: 1.0557x; 1.0557x over previous
//
#include <hip/hip_runtime.h>
#include <hip/hip_bf16.h>

// ---------------------------------------------------------------------------
// AttentionHeteroConv. R5 = R4's conflict-free LDS layout + R3's low register
// pressure. Staging loops NOT pragma-unrolled (R4's unroll pragmas caused
// accumulator spill -> 13 GB scratch traffic). LDS overlay via union.
// ---------------------------------------------------------------------------

#define C 128
#define NHEAD 4
#define DH 32
#define QK_SCALE 0.17677669529663687f  // 1/sqrt(32)

// ---------------------------------------------------------------------------
// K2: transform: h = x@Wnb^T + bnb ; self = x@Wself^T + bself
// M=32 rows/block, N=256 (0-127 Wnb, 128-255 Wself), K=128.
// ---------------------------------------------------------------------------
__global__ __launch_bounds__(256) void transform_kernel(
    const float* __restrict__ x, int n_rows,
    const float* __restrict__ Wnb, const float* __restrict__ bnb,
    const float* __restrict__ Wself, const float* __restrict__ bself,
    float* __restrict__ h, float* __restrict__ selfout)
{
    __shared__ float As[32 * 132];
    __shared__ float4 Bs4[8 * 257];
    __shared__ float biasS[256];

    const int tid = threadIdx.x;
    const int row0 = blockIdx.x * 32;

    if (tid < 128) biasS[tid] = bnb[tid];
    else           biasS[tid] = bself[tid - 128];

    for (int i = 0; i < 4; i++) {
        int id = tid + i * 256;              // 1024 = 32 rows x 32 f4
        int r = id >> 5, c4 = id & 31;
        float4 v = make_float4(0.f, 0.f, 0.f, 0.f);
        if (row0 + r < n_rows) v = ((const float4*)x)[(size_t)(row0 + r) * 32 + c4];
        *(float4*)&As[r * 132 + c4 * 4] = v;
    }

    const int tn = tid & 31;
    const int tm = tid >> 5;
    float acc[4][8];
#pragma unroll
    for (int m = 0; m < 4; m++)
#pragma unroll
        for (int j = 0; j < 8; j++) acc[m][j] = 0.f;

    const float4* Wnb4 = (const float4*)Wnb;
    const float4* Wsf4 = (const float4*)Wself;

    for (int ks = 0; ks < 4; ks++) {
        __syncthreads();
        for (int i = 0; i < 8; i++) {
            int id = tid + i * 256;          // 2048 = 256 n x 8 k4
            int n = id >> 3, k4 = id & 7;
            const float4* Wp = (i < 4) ? Wnb4 : Wsf4;
            Bs4[k4 * 257 + n] = Wp[(size_t)(n & 127) * 32 + ks * 8 + k4];
        }
        __syncthreads();
#pragma unroll
        for (int k4 = 0; k4 < 8; k4++) {
            float4 a[4];
#pragma unroll
            for (int m = 0; m < 4; m++)
                a[m] = *(const float4*)&As[(tm * 4 + m) * 132 + ks * 32 + k4 * 4];
#pragma unroll
            for (int j = 0; j < 8; j++) {
                float4 b = Bs4[k4 * 257 + tn + 32 * j];
#pragma unroll
                for (int m = 0; m < 4; m++)
                    acc[m][j] += a[m].x * b.x + a[m].y * b.y
                               + a[m].z * b.z + a[m].w * b.w;
            }
        }
    }

#pragma unroll
    for (int m = 0; m < 4; m++) {
        int row = row0 + tm * 4 + m;
        if (row < n_rows) {
#pragma unroll
            for (int j = 0; j < 8; j++) {
                int col = tn + 32 * j;
                float v = acc[m][j] + biasS[col];
                if (j < 4) h[(size_t)row * C + col] = v;
                else       selfout[(size_t)row * C + col - 128] = v;
            }
        }
    }
}

// ---------------------------------------------------------------------------
// CSR build: zero + histogram + exclusive-scan (single block) + fill.
// ---------------------------------------------------------------------------
__global__ __launch_bounds__(256) void zero_kernel(int* __restrict__ p, int n)
{
    int i = blockIdx.x * 256 + threadIdx.x;
    if (i < n) p[i] = 0;
}

__global__ __launch_bounds__(256) void hist_kernel(
    const int* __restrict__ dst, int n, int* __restrict__ cur)
{
    int i = blockIdx.x * 256 + threadIdx.x;
    if (i < n) atomicAdd(&cur[dst[i]], 1);
}

__global__ __launch_bounds__(1024) void scan_kernel(int* __restrict__ cur, int n)
{
    __shared__ int wsum[16];
    __shared__ int carryS;
    const int tid = threadIdx.x, lane = tid & 63, wv = tid >> 6;
    if (tid == 0) carryS = 0;
    __syncthreads();
    for (int base = 0; base < n; base += 1024) {
        int i = base + tid;
        int v = (i < n) ? cur[i] : 0;
        int x = v;
#pragma unroll
        for (int d = 1; d < 64; d <<= 1) {
            int t = __shfl_up(x, d, 64);
            if (lane >= d) x += t;
        }
        if (lane == 63) wsum[wv] = x;
        int carry = carryS;
        __syncthreads();
        int wpre = 0;
#pragma unroll
        for (int w2 = 0; w2 < 16; w2++) wpre += (w2 < wv) ? wsum[w2] : 0;
        int excl = x - v + wpre + carry;
        if (i < n) cur[i] = excl;
        __syncthreads();
        if (tid == 0) {
            int t = 0;
#pragma unroll
            for (int w2 = 0; w2 < 16; w2++) t += wsum[w2];
            carryS = carry + t;
        }
        __syncthreads();
    }
}

__global__ __launch_bounds__(256) void fill_kernel(
    const int* __restrict__ src, const int* __restrict__ dst, int n,
    int* __restrict__ cur, int* __restrict__ csr)
{
    int i = blockIdx.x * 256 + threadIdx.x;
    if (i < n) {
        int p = atomicAdd(&cur[dst[i]], 1);
        csr[p] = src[i];
    }
}

// ---------------------------------------------------------------------------
// K4: fused gather-aggregate + qkv-GEMM + attention, 8 nodes/block.
// LDS union: GEMM phase {As[32][132], Bs[8][385] float4} / attn phase
// qkv[40][388] (rows node*5+s; q 0-127, k 128-255, v 256-383).
// ---------------------------------------------------------------------------
#define ATN 8
#define QROW 388

union AttnSmem {
    struct { float As[32 * 132]; float4 Bs[8 * 385]; } g;
    float qkv[40 * QROW];
};

__global__ __launch_bounds__(256, 2) void attn_fused_kernel(
    const float* __restrict__ h_src, const int* __restrict__ csr,
    const int* __restrict__ cur, const float* __restrict__ selfF,
    const float* __restrict__ Wip, const float* __restrict__ bip,
    float* __restrict__ omean_g, int n_nodes)
{
    __shared__ AttnSmem sm;
    __shared__ float attS[ATN * NHEAD * 25];
    __shared__ float bipS[384];
    __shared__ float cinv[ATN];

    const int tid = threadIdx.x;
    const int lane = tid & 63;
    const int wv = tid >> 6;
    const int node0 = blockIdx.x * ATN;

    // ---- P0a: stage bip + self rows (A rows nl*4+0) ----
    for (int i = tid; i < 384; i += 256) bipS[i] = bip[i];
    {
        int r = tid >> 5, c4 = tid & 31;
        int node = node0 + r;
        float4 v = make_float4(0.f, 0.f, 0.f, 0.f);
        if (node < n_nodes) v = ((const float4*)selfF)[(size_t)node * 32 + c4];
        *(float4*)&sm.g.As[(r * 4 + 0) * 132 + c4 * 4] = v;
    }

    // ---- P0b: gather max/min/sum (A rows nl*4+{1,2,3}), 2 nodes/wave ----
    const float2* h2 = (const float2*)h_src;
#pragma unroll
    for (int half = 0; half < 2; half++) {
        int nl = wv * 2 + half;
        int node = node0 + nl;
        float2 vs = make_float2(0.f, 0.f);
        float2 vmx = make_float2(-3.4e38f, -3.4e38f);
        float2 vmn = make_float2(3.4e38f, 3.4e38f);
        int deg = 0;
        if (node < n_nodes) {
            int start = (node == 0) ? 0 : cur[node - 1];
            int end = cur[node];
            deg = end - start;
            int e = start;
            for (; e + 4 <= end; e += 4) {
                int s0 = csr[e], s1 = csr[e + 1], s2 = csr[e + 2], s3 = csr[e + 3];
                float2 v0 = h2[(size_t)s0 * 64 + lane];
                float2 v1 = h2[(size_t)s1 * 64 + lane];
                float2 v2 = h2[(size_t)s2 * 64 + lane];
                float2 v3 = h2[(size_t)s3 * 64 + lane];
                vs.x += v0.x + v1.x + v2.x + v3.x;
                vs.y += v0.y + v1.y + v2.y + v3.y;
                vmx.x = fmaxf(fmaxf(vmx.x, v0.x), fmaxf(v1.x, fmaxf(v2.x, v3.x)));
                vmx.y = fmaxf(fmaxf(vmx.y, v0.y), fmaxf(v1.y, fmaxf(v2.y, v3.y)));
                vmn.x = fminf(fminf(vmn.x, v0.x), fminf(v1.x, fminf(v2.x, v3.x)));
                vmn.y = fminf(fminf(vmn.y, v0.y), fminf(v1.y, fminf(v2.y, v3.y)));
            }
            for (; e < end; e++) {
                int s0 = csr[e];
                float2 v0 = h2[(size_t)s0 * 64 + lane];
                vs.x += v0.x; vs.y += v0.y;
                vmx.x = fmaxf(vmx.x, v0.x); vmx.y = fmaxf(vmx.y, v0.y);
                vmn.x = fminf(vmn.x, v0.x); vmn.y = fminf(vmn.y, v0.y);
            }
        }
        if (deg == 0) {
            vmx = make_float2(0.f, 0.f);
            vmn = make_float2(0.f, 0.f);
        }
        *(float2*)&sm.g.As[(nl * 4 + 1) * 132 + 2 * lane] = vmx;
        *(float2*)&sm.g.As[(nl * 4 + 2) * 132 + 2 * lane] = vmn;
        *(float2*)&sm.g.As[(nl * 4 + 3) * 132 + 2 * lane] = vs;
        if (lane == 0) cinv[nl] = 1.f / (float)max(deg, 1);
    }

    // ---- P1: GEMM qkv = A @ Wip^T  (M=32, N=384, K=128) ----
    const int tn = tid & 31;
    const int tm = tid >> 5;
    float acc[4][12];
#pragma unroll
    for (int m = 0; m < 4; m++)
#pragma unroll
        for (int j = 0; j < 12; j++) acc[m][j] = 0.f;

    const float4* Wip4 = (const float4*)Wip;

    for (int ks = 0; ks < 4; ks++) {
        __syncthreads();
        for (int i = 0; i < 12; i++) {       // plain loop: keep VGPR pressure low
            int id = tid + i * 256;          // 3072 = 384 n x 8 k4
            int n = id >> 3, k4 = id & 7;
            sm.g.Bs[k4 * 385 + n] = Wip4[(size_t)n * 32 + ks * 8 + k4];
        }
        __syncthreads();
#pragma unroll
        for (int k4 = 0; k4 < 8; k4++) {
            float4 a[4];
#pragma unroll
            for (int m = 0; m < 4; m++)
                a[m] = *(const float4*)&sm.g.As[(tm * 4 + m) * 132 + ks * 32 + k4 * 4];
#pragma unroll
            for (int j = 0; j < 12; j++) {
                float4 b = sm.g.Bs[k4 * 385 + tn + 32 * j];
#pragma unroll
                for (int m = 0; m < 4; m++)
                    acc[m][j] += a[m].x * b.x + a[m].y * b.y
                               + a[m].z * b.z + a[m].w * b.w;
            }
        }
    }

    // ---- P2: C-tile (+bias) -> qkv overlay rows node*5+s ----
    __syncthreads();
#pragma unroll
    for (int m = 0; m < 4; m++) {
        int mr = tm * 4 + m;
        int node = mr >> 2, s = mr & 3;
        float* q = &sm.qkv[(node * 5 + s) * QROW];
#pragma unroll
        for (int j = 0; j < 12; j++) {
            int n = tn + 32 * j;
            q[n] = acc[m][j] + bipS[n];
        }
    }
    __syncthreads();

    // ---- P3: mean rows: (qkv_sum - b)*cinv + b ----
    for (int i = 0; i < 12; i++) {
        int id = tid + i * 256;              // 3072 = 8 x 384
        int n = id / 384, c = id - n * 384;
        float b = bipS[c];
        sm.qkv[(n * 5 + 4) * QROW + c] = (sm.qkv[(n * 5 + 3) * QROW + c] - b) * cinv[n] + b;
    }
    __syncthreads();

    // ---- P4a: scores, all heads (threads: n,i,j) ----
    if (tid < ATN * 25) {
        int n = tid / 25, r = tid - n * 25, i = r / 5, j = r - (r / 5) * 5;
        const float4* qr = (const float4*)&sm.qkv[(n * 5 + i) * QROW];
        const float4* kr = (const float4*)&sm.qkv[(n * 5 + j) * QROW + C];
#pragma unroll
        for (int h = 0; h < NHEAD; h++) {
            float s = 0.f;
#pragma unroll
            for (int d4 = 0; d4 < 8; d4++) {
                float4 q = qr[h * 8 + d4];
                float4 k = kr[h * 8 + d4];
                s += q.x * k.x + q.y * k.y + q.z * k.z + q.w * k.w;
            }
            attS[((n * NHEAD + h) * 5 + i) * 5 + j] = s * QK_SCALE;
        }
    }
    __syncthreads();

    // ---- P4b: softmax rows (threads: n,h,i), fold 1/5 ----
    if (tid < ATN * NHEAD * 5) {
        int n = tid / 20, r = tid - n * 20, h = r / 5, i = r - (r / 5) * 5;
        float* a = &attS[((n * NHEAD + h) * 5 + i) * 5];
        float m = a[0];
#pragma unroll
        for (int j = 1; j < 5; j++) m = fmaxf(m, a[j]);
        float e[5], l = 0.f;
#pragma unroll
        for (int j = 0; j < 5; j++) { e[j] = __expf(a[j] - m); l += e[j]; }
        float inv = 0.2f / l;
#pragma unroll
        for (int j = 0; j < 5; j++) a[j] = e[j] * inv;
    }
    __syncthreads();

    // ---- P4c: PV via column-summed weights -> omean_g directly ----
    for (int it = 0; it < 4; it++) {
        int id = tid + it * 256;             // 1024 = 8 n x 128 c
        int n = id >> 7, c = id & 127, h = c >> 5;
        const float* ab = &attS[(n * NHEAD + h) * 25];
        float o = 0.f;
#pragma unroll
        for (int j = 0; j < 5; j++) {
            float wj = ab[0 * 5 + j] + ab[1 * 5 + j] + ab[2 * 5 + j]
                     + ab[3 * 5 + j] + ab[4 * 5 + j];
            o += wj * sm.qkv[(n * 5 + j) * QROW + 2 * C + c];
        }
        int node = node0 + n;
        if (node < n_nodes) omean_g[(size_t)node * C + c] = o;
    }
}

// ---------------------------------------------------------------------------
// K5: out = self(d_out) + omean @ Wop^T + bop.  M=32/block, N=128, K=128.
// ---------------------------------------------------------------------------
__global__ __launch_bounds__(256, 4) void outproj_kernel(
    const float* __restrict__ omean_g, const float* __restrict__ Wop,
    const float* __restrict__ bop, float* __restrict__ out, int M)
{
    __shared__ float As[32 * 132];
    __shared__ float4 Bs4[8 * 129];
    __shared__ float bopS[C];

    const int tid = threadIdx.x;
    const int m0 = blockIdx.x * 32;

    if (tid < C) bopS[tid] = bop[tid];
    for (int i = 0; i < 4; i++) {
        int id = tid + i * 256;
        int r = id >> 5, c4 = id & 31;
        float4 v = make_float4(0.f, 0.f, 0.f, 0.f);
        int m = m0 + r;
        if (m < M) v = ((const float4*)omean_g)[(size_t)m * 32 + c4];
        *(float4*)&As[r * 132 + c4 * 4] = v;
    }

    const int tn = tid & 31;
    const int tm = tid >> 5;
    float acc[4][4];
#pragma unroll
    for (int m = 0; m < 4; m++)
#pragma unroll
        for (int j = 0; j < 4; j++) acc[m][j] = 0.f;

    const float4* Wop4 = (const float4*)Wop;

    for (int ks = 0; ks < 4; ks++) {
        __syncthreads();
        for (int i = 0; i < 4; i++) {
            int id = tid + i * 256;          // 1024 = 128 n x 8 k4
            int n = id >> 3, k4 = id & 7;
            Bs4[k4 * 129 + n] = Wop4[(size_t)n * 32 + ks * 8 + k4];
        }
        __syncthreads();
#pragma unroll
        for (int k4 = 0; k4 < 8; k4++) {
            float4 a[4];
#pragma unroll
            for (int m = 0; m < 4; m++)
                a[m] = *(const float4*)&As[(tm * 4 + m) * 132 + ks * 32 + k4 * 4];
#pragma unroll
            for (int j = 0; j < 4; j++) {
                float4 b = Bs4[k4 * 129 + tn + 32 * j];
#pragma unroll
                for (int m = 0; m < 4; m++)
                    acc[m][j] += a[m].x * b.x + a[m].y * b.y
                               + a[m].z * b.z + a[m].w * b.w;
            }
        }
    }

#pragma unroll
    for (int m = 0; m < 4; m++) {
        int row = m0 + tm * 4 + m;
        if (row < M) {
#pragma unroll
            for (int j = 0; j < 4; j++) {
                int col = tn + 32 * j;
                float* p = &out[(size_t)row * C + col];
                *p += acc[m][j] + bopS[col];
            }
        }
    }
}

// ---------------------------------------------------------------------------
extern "C" void kernel_launch(void* const* d_in, const int* in_sizes, int n_in,
                              void* d_out, int out_size, void* d_ws, size_t ws_size,
                              hipStream_t stream) {
    const float* x_user = (const float*)d_in[0];
    const float* x_item = (const float*)d_in[1];
    const int*   ei_u2i = (const int*)d_in[2];
    const int*   ei_i2u = (const int*)d_in[3];
    const float* W_nb   = (const float*)d_in[4];
    const float* b_nb   = (const float*)d_in[5];
    const float* W_self = (const float*)d_in[6];
    const float* b_self = (const float*)d_in[7];
    const float* Wip    = (const float*)d_in[8];
    const float* bip    = (const float*)d_in[9];
    const float* Wop    = (const float*)d_in[10];
    const float* bop    = (const float*)d_in[11];

    const int NU = in_sizes[0] / C;
    const int NI = in_sizes[1] / C;
    const int E1 = in_sizes[2] / 2;
    const int E2 = in_sizes[3] / 2;

    float* out_user = (float*)d_out;
    float* out_item = out_user + (size_t)NU * C;

    // workspace: h (rc) | omean (rc) | cur (maxN ints) | csr (maxE ints)
    float* ws = (float*)d_ws;
    const size_t rc = (size_t)(NU + NI) * C;
    float* h_all     = ws;
    float* omean_all = h_all + rc;
    int*   cur       = (int*)(omean_all + rc);
    const int maxN   = (NU > NI) ? NU : NI;
    int*   csr       = cur + maxN;

    float* h_user = h_all;
    float* h_item = h_all + (size_t)NU * C;
    float* om_user = omean_all;
    float* om_item = omean_all + (size_t)NU * C;

    transform_kernel<<<(NU + 31) / 32, 256, 0, stream>>>(
        x_user, NU, W_nb, b_nb, W_self, b_self, h_user, out_user);
    transform_kernel<<<(NI + 31) / 32, 256, 0, stream>>>(
        x_item, NI, W_nb, b_nb, W_self, b_self, h_item, out_item);

    // direction A: user -> item
    zero_kernel<<<(NI + 255) / 256, 256, 0, stream>>>(cur, NI);
    hist_kernel<<<(E1 + 255) / 256, 256, 0, stream>>>(ei_u2i + E1, E1, cur);
    scan_kernel<<<1, 1024, 0, stream>>>(cur, NI);
    fill_kernel<<<(E1 + 255) / 256, 256, 0, stream>>>(ei_u2i, ei_u2i + E1, E1, cur, csr);
    attn_fused_kernel<<<(NI + ATN - 1) / ATN, 256, 0, stream>>>(
        h_user, csr, cur, out_item, Wip, bip, om_item, NI);

    // direction B: item -> user
    zero_kernel<<<(NU + 255) / 256, 256, 0, stream>>>(cur, NU);
    hist_kernel<<<(E2 + 255) / 256, 256, 0, stream>>>(ei_i2u + E2, E2, cur);
    scan_kernel<<<1, 1024, 0, stream>>>(cur, NU);
    fill_kernel<<<(E2 + 255) / 256, 256, 0, stream>>>(ei_i2u, ei_i2u + E2, E2, cur, csr);
    attn_fused_kernel<<<(NU + ATN - 1) / ATN, 256, 0, stream>>>(
        h_item, csr, cur, out_user, Wip, bip, om_user, NU);

    outproj_kernel<<<(NU + NI + 31) / 32, 256, 0, stream>>>(
        omean_all, Wop, bop, (float*)d_out, NU + NI);
}

// Round 6
// 1716.266 us; speedup vs baseline: 4.6172x; 4.3734x over previous
//
#include <hip/hip_runtime.h>
#include <hip/hip_bf16.h>

// ---------------------------------------------------------------------------
// AttentionHeteroConv. R6 = R3 verbatim with ONE change: attn GEMM B-tile in
// conflict-free float4 layout (Bs4[k4][n], stride 385 f4; staging is
// float4->float4; B-reads lane-consecutive b128; n-columns interleaved).
// Everything else (transform, csr, tail, outproj) is R3's measured-good code.
// ---------------------------------------------------------------------------

#define C 128
#define NHEAD 4
#define DH 32
#define QK_SCALE 0.17677669529663687f  // 1/sqrt(32)

// ---------------------------------------------------------------------------
// K2: transform: h = x@Wnb^T + bnb ; self = x@Wself^T + bself  (R3 version)
// ---------------------------------------------------------------------------
__global__ __launch_bounds__(256) void transform_kernel(
    const float* __restrict__ x, int n_rows,
    const float* __restrict__ Wnb, const float* __restrict__ bnb,
    const float* __restrict__ Wself, const float* __restrict__ bself,
    float* __restrict__ h, float* __restrict__ selfout)
{
    __shared__ float At[32][C];
    const int tid = threadIdx.x;
    const int row0 = blockIdx.x * 32;

    for (int i = tid; i < 32 * 32; i += 256) {
        int r = i >> 5, c4 = i & 31;
        float4 v = make_float4(0.f, 0.f, 0.f, 0.f);
        if (row0 + r < n_rows) v = ((const float4*)x)[(size_t)(row0 + r) * 32 + c4];
        ((float4*)At[r])[c4] = v;
    }
    __syncthreads();

    const int col = tid & 127;
    const float* W = (tid < 128) ? Wnb : Wself;
    const float* bb = (tid < 128) ? bnb : bself;
    float* outp = (tid < 128) ? h : selfout;

    float acc[32];
#pragma unroll
    for (int r = 0; r < 32; r++) acc[r] = 0.f;

    const float4* w4 = (const float4*)(W + (size_t)col * C);
    for (int k4 = 0; k4 < 32; k4 += 4) {
        float4 w0 = w4[k4], w1 = w4[k4 + 1], w2 = w4[k4 + 2], w3 = w4[k4 + 3];
#pragma unroll
        for (int r = 0; r < 32; r++) {
            const float4* a4 = (const float4*)At[r];
            float4 a0 = a4[k4], a1 = a4[k4 + 1], a2 = a4[k4 + 2], a3 = a4[k4 + 3];
            acc[r] += a0.x * w0.x + a0.y * w0.y + a0.z * w0.z + a0.w * w0.w
                    + a1.x * w1.x + a1.y * w1.y + a1.z * w1.z + a1.w * w1.w
                    + a2.x * w2.x + a2.y * w2.y + a2.z * w2.z + a2.w * w2.w
                    + a3.x * w3.x + a3.y * w3.y + a3.z * w3.z + a3.w * w3.w;
        }
    }
    const float bias = bb[col];
#pragma unroll
    for (int r = 0; r < 32; r++) {
        int row = row0 + r;
        if (row < n_rows) outp[(size_t)row * C + col] = acc[r] + bias;
    }
}

// ---------------------------------------------------------------------------
// CSR build: zero + histogram + exclusive-scan (single block) + fill.
// ---------------------------------------------------------------------------
__global__ __launch_bounds__(256) void zero_kernel(int* __restrict__ p, int n)
{
    int i = blockIdx.x * 256 + threadIdx.x;
    if (i < n) p[i] = 0;
}

__global__ __launch_bounds__(256) void hist_kernel(
    const int* __restrict__ dst, int n, int* __restrict__ cur)
{
    int i = blockIdx.x * 256 + threadIdx.x;
    if (i < n) atomicAdd(&cur[dst[i]], 1);
}

__global__ __launch_bounds__(1024) void scan_kernel(int* __restrict__ cur, int n)
{
    __shared__ int wsum[16];
    __shared__ int carryS;
    const int tid = threadIdx.x, lane = tid & 63, wv = tid >> 6;
    if (tid == 0) carryS = 0;
    __syncthreads();
    for (int base = 0; base < n; base += 1024) {
        int i = base + tid;
        int v = (i < n) ? cur[i] : 0;
        int x = v;
#pragma unroll
        for (int d = 1; d < 64; d <<= 1) {
            int t = __shfl_up(x, d, 64);
            if (lane >= d) x += t;
        }
        if (lane == 63) wsum[wv] = x;
        int carry = carryS;
        __syncthreads();
        int wpre = 0;
#pragma unroll
        for (int w2 = 0; w2 < 16; w2++) wpre += (w2 < wv) ? wsum[w2] : 0;
        int excl = x - v + wpre + carry;
        if (i < n) cur[i] = excl;
        __syncthreads();
        if (tid == 0) {
            int t = 0;
#pragma unroll
            for (int w2 = 0; w2 < 16; w2++) t += wsum[w2];
            carryS = carry + t;
        }
        __syncthreads();
    }
}

__global__ __launch_bounds__(256) void fill_kernel(
    const int* __restrict__ src, const int* __restrict__ dst, int n,
    int* __restrict__ cur, int* __restrict__ csr)
{
    int i = blockIdx.x * 256 + threadIdx.x;
    if (i < n) {
        int p = atomicAdd(&cur[dst[i]], 1);
        csr[p] = src[i];
    }
}

// ---------------------------------------------------------------------------
// K4: fused gather-aggregate + qkv-GEMM + attention, 8 nodes/block.
// R3 structure. LDS region R (floats):
//   GEMM:    As[32][132] @0,  Bs4 = float4[8][385] @float-offset 4224
//   overlay: qkv[40][384] @0  (rows node*5+s)
// ---------------------------------------------------------------------------
#define ATN 8
#define AS_F 4224
#define RSZ 16544            // 4224 + 8*385*4 floats = 66176 B; overlay needs 15360

__global__ __launch_bounds__(256, 2) void attn_fused_kernel(
    const float* __restrict__ h_src, const int* __restrict__ csr,
    const int* __restrict__ cur, const float* __restrict__ selfF,
    const float* __restrict__ Wip, const float* __restrict__ bip,
    float* __restrict__ omean_g, int n_nodes)
{
    __shared__ float R[RSZ];
    __shared__ float omean[ATN][C];
    __shared__ float att[ATN][5][5];
    __shared__ float bipS[384];
    __shared__ float cinv[ATN];

    const int tid = threadIdx.x;
    const int lane = tid & 63;
    const int wv = tid >> 6;
    const int node0 = blockIdx.x * ATN;

    // ---- P0a: stage bip + self rows ----
    for (int i = tid; i < 384; i += 256) bipS[i] = bip[i];
    {
        int r = tid >> 5, c4 = tid & 31;
        int node = node0 + r;
        float4 v = make_float4(0.f, 0.f, 0.f, 0.f);
        if (node < n_nodes) v = ((const float4*)selfF)[(size_t)node * 32 + c4];
        *(float4*)&R[(r * 4 + 0) * 132 + c4 * 4] = v;
    }

    // ---- P0b: gather max/min/sum, 2 nodes per wave ----
    const float2* h2 = (const float2*)h_src;
#pragma unroll
    for (int half = 0; half < 2; half++) {
        int nl = wv * 2 + half;
        int node = node0 + nl;
        float2 vs = make_float2(0.f, 0.f);
        float2 vmx = make_float2(-3.4e38f, -3.4e38f);
        float2 vmn = make_float2(3.4e38f, 3.4e38f);
        int deg = 0;
        if (node < n_nodes) {
            int start = (node == 0) ? 0 : cur[node - 1];
            int end = cur[node];
            deg = end - start;
            int e = start;
            for (; e + 4 <= end; e += 4) {
                int s0 = csr[e], s1 = csr[e + 1], s2 = csr[e + 2], s3 = csr[e + 3];
                float2 v0 = h2[(size_t)s0 * 64 + lane];
                float2 v1 = h2[(size_t)s1 * 64 + lane];
                float2 v2 = h2[(size_t)s2 * 64 + lane];
                float2 v3 = h2[(size_t)s3 * 64 + lane];
                vs.x += v0.x + v1.x + v2.x + v3.x;
                vs.y += v0.y + v1.y + v2.y + v3.y;
                vmx.x = fmaxf(fmaxf(vmx.x, v0.x), fmaxf(v1.x, fmaxf(v2.x, v3.x)));
                vmx.y = fmaxf(fmaxf(vmx.y, v0.y), fmaxf(v1.y, fmaxf(v2.y, v3.y)));
                vmn.x = fminf(fminf(vmn.x, v0.x), fminf(v1.x, fminf(v2.x, v3.x)));
                vmn.y = fminf(fminf(vmn.y, v0.y), fminf(v1.y, fminf(v2.y, v3.y)));
            }
            for (; e < end; e++) {
                int s0 = csr[e];
                float2 v0 = h2[(size_t)s0 * 64 + lane];
                vs.x += v0.x; vs.y += v0.y;
                vmx.x = fmaxf(vmx.x, v0.x); vmx.y = fmaxf(vmx.y, v0.y);
                vmn.x = fminf(vmn.x, v0.x); vmn.y = fminf(vmn.y, v0.y);
            }
        }
        if (deg == 0) {
            vmx = make_float2(0.f, 0.f);
            vmn = make_float2(0.f, 0.f);
        }
        *(float2*)&R[(nl * 4 + 1) * 132 + 2 * lane] = vmx;
        *(float2*)&R[(nl * 4 + 2) * 132 + 2 * lane] = vmn;
        *(float2*)&R[(nl * 4 + 3) * 132 + 2 * lane] = vs;
        if (lane == 0) cinv[nl] = 1.f / (float)max(deg, 1);
    }

    // ---- P1: GEMM qkv = A @ Wip^T  (M=32, N=384, K=128) ----
    const int tn = tid & 31;
    const int tm = tid >> 5;
    float acc[4][12];
#pragma unroll
    for (int m = 0; m < 4; m++)
#pragma unroll
        for (int j = 0; j < 12; j++) acc[m][j] = 0.f;

    const float4* Wip4 = (const float4*)Wip;
    float4* Bs4 = (float4*)&R[AS_F];     // [8][385] float4, 16B-aligned

    for (int ks = 0; ks < 4; ks++) {
        __syncthreads();
        for (int i = 0; i < 12; i++) {
            int id = tid + i * 256;          // 3072 = 384 n x 8 k4
            int n = id >> 3, k4 = id & 7;
            Bs4[k4 * 385 + n] = Wip4[(size_t)n * 32 + ks * 8 + k4];
        }
        __syncthreads();
#pragma unroll 2
        for (int k4 = 0; k4 < 8; k4++) {
            float4 a[4];
#pragma unroll
            for (int m = 0; m < 4; m++)
                a[m] = *(const float4*)&R[(tm * 4 + m) * 132 + ks * 32 + k4 * 4];
#pragma unroll
            for (int j = 0; j < 12; j++) {
                float4 b = Bs4[k4 * 385 + tn + 32 * j];
#pragma unroll
                for (int m = 0; m < 4; m++)
                    acc[m][j] += a[m].x * b.x + a[m].y * b.y
                               + a[m].z * b.z + a[m].w * b.w;
            }
        }
    }

    // ---- P2: C-tile (+bias) -> qkv overlay rows node*5+s ----
    __syncthreads();
#pragma unroll
    for (int m = 0; m < 4; m++) {
        int mr = tm * 4 + m;
        int node = mr >> 2, s = mr & 3;
        float* q = &R[(node * 5 + s) * 384];
#pragma unroll
        for (int j = 0; j < 12; j++) {
            int n = tn + 32 * j;
            q[n] = acc[m][j] + bipS[n];
        }
    }
    __syncthreads();

    // ---- P3: derive mean rows: (qkv_sum - b)*cinv + b ----
    for (int i = 0; i < 12; i++) {
        int id = tid + i * 256;              // 3072 = 8 x 384
        int n = id / 384, c = id - n * 384;
        float b = bipS[c];
        R[(n * 5 + 4) * 384 + c] = (R[(n * 5 + 3) * 384 + c] - b) * cinv[n] + b;
    }
    __syncthreads();

    // ---- P4: per-head scores/softmax/PV (R3 tail) ----
    for (int h = 0; h < NHEAD; h++) {
        if (tid < ATN * 25) {
            int n = tid / 25, ij = tid - n * 25, i = ij / 5, j = ij - (ij / 5) * 5;
            const float* qr = &R[(n * 5 + i) * 384 + h * DH];
            const float* kr = &R[(n * 5 + j) * 384 + C + h * DH];
            float s = 0.f;
#pragma unroll
            for (int d = 0; d < DH; d++) s += qr[d] * kr[d];
            att[n][i][j] = s * QK_SCALE;
        }
        __syncthreads();
        if (tid < ATN * 5) {
            int n = tid / 5, i = tid - n * 5;
            float m = att[n][i][0];
#pragma unroll
            for (int j = 1; j < 5; j++) m = fmaxf(m, att[n][i][j]);
            float e[5], l = 0.f;
#pragma unroll
            for (int j = 0; j < 5; j++) { e[j] = __expf(att[n][i][j] - m); l += e[j]; }
            float inv = 0.2f / l;
#pragma unroll
            for (int j = 0; j < 5; j++) att[n][i][j] = e[j] * inv;
        }
        __syncthreads();
        {
            int n = tid >> 5, d = tid & 31;
            float a2 = 0.f;
#pragma unroll
            for (int j = 0; j < 5; j++) {
                float wj = att[n][0][j] + att[n][1][j] + att[n][2][j]
                         + att[n][3][j] + att[n][4][j];
                a2 += wj * R[(n * 5 + j) * 384 + 2 * C + h * DH + d];
            }
            omean[n][h * DH + d] = a2;
        }
        __syncthreads();
    }

    // ---- P5: omean -> global ----
#pragma unroll
    for (int i = 0; i < 4; i++) {
        int id = tid + i * 256;
        int n = id >> 7, c = id & 127;
        int node = node0 + n;
        if (node < n_nodes) omean_g[(size_t)node * C + c] = omean[n][c];
    }
}

// ---------------------------------------------------------------------------
// K5: out = self(d_out) + omean @ Wop^T + bop.  (R3 version)
// ---------------------------------------------------------------------------
__global__ __launch_bounds__(256, 4) void outproj_kernel(
    const float* __restrict__ omean_g, const float* __restrict__ Wop,
    const float* __restrict__ bop, float* __restrict__ out, int M)
{
    __shared__ float As[32 * 132];
    __shared__ float Bs[32 * 132];
    __shared__ float bopS[C];
    const int tid = threadIdx.x;
    const int m0 = blockIdx.x * 32;

    if (tid < C) bopS[tid] = bop[tid];
#pragma unroll
    for (int i = 0; i < 4; i++) {
        int id = tid + i * 256;
        int r = id >> 5, c4 = id & 31;
        float4 v = make_float4(0.f, 0.f, 0.f, 0.f);
        int m = m0 + r;
        if (m < M) v = ((const float4*)omean_g)[(size_t)m * 32 + c4];
        *(float4*)&As[r * 132 + c4 * 4] = v;
    }

    const int tn = tid & 31;
    const int tm = tid >> 5;
    float acc[4][4];
#pragma unroll
    for (int m = 0; m < 4; m++)
#pragma unroll
        for (int n = 0; n < 4; n++) acc[m][n] = 0.f;

    for (int ks = 0; ks < 4; ks++) {
        __syncthreads();
        for (int i = 0; i < 4; i++) {
            int id = tid + i * 256;          // 1024 = 128 n x 8 q
            int n = id >> 3, q = id & 7;
            float4 w = ((const float4*)Wop)[(size_t)n * 32 + ks * 8 + q];
            Bs[(q * 4 + 0) * 132 + n] = w.x;
            Bs[(q * 4 + 1) * 132 + n] = w.y;
            Bs[(q * 4 + 2) * 132 + n] = w.z;
            Bs[(q * 4 + 3) * 132 + n] = w.w;
        }
        __syncthreads();
#pragma unroll 4
        for (int k4 = 0; k4 < 8; k4++) {
            float4 a[4];
#pragma unroll
            for (int m = 0; m < 4; m++)
                a[m] = *(const float4*)&As[(tm * 4 + m) * 132 + ks * 32 + k4 * 4];
#pragma unroll
            for (int kk = 0; kk < 4; kk++) {
                float4 b = *(const float4*)&Bs[(k4 * 4 + kk) * 132 + tn * 4];
#pragma unroll
                for (int m = 0; m < 4; m++) {
                    float av = ((const float*)&a[m])[kk];
                    acc[m][0] += av * b.x; acc[m][1] += av * b.y;
                    acc[m][2] += av * b.z; acc[m][3] += av * b.w;
                }
            }
        }
    }

#pragma unroll
    for (int m = 0; m < 4; m++) {
        int row = m0 + tm * 4 + m;
        if (row < M) {
            float4* o = (float4*)&out[(size_t)row * C + tn * 4];
            float4 r = *o;
            r.x += acc[m][0] + bopS[tn * 4 + 0];
            r.y += acc[m][1] + bopS[tn * 4 + 1];
            r.z += acc[m][2] + bopS[tn * 4 + 2];
            r.w += acc[m][3] + bopS[tn * 4 + 3];
            *o = r;
        }
    }
}

// ---------------------------------------------------------------------------
extern "C" void kernel_launch(void* const* d_in, const int* in_sizes, int n_in,
                              void* d_out, int out_size, void* d_ws, size_t ws_size,
                              hipStream_t stream) {
    const float* x_user = (const float*)d_in[0];
    const float* x_item = (const float*)d_in[1];
    const int*   ei_u2i = (const int*)d_in[2];
    const int*   ei_i2u = (const int*)d_in[3];
    const float* W_nb   = (const float*)d_in[4];
    const float* b_nb   = (const float*)d_in[5];
    const float* W_self = (const float*)d_in[6];
    const float* b_self = (const float*)d_in[7];
    const float* Wip    = (const float*)d_in[8];
    const float* bip    = (const float*)d_in[9];
    const float* Wop    = (const float*)d_in[10];
    const float* bop    = (const float*)d_in[11];

    const int NU = in_sizes[0] / C;
    const int NI = in_sizes[1] / C;
    const int E1 = in_sizes[2] / 2;
    const int E2 = in_sizes[3] / 2;

    float* out_user = (float*)d_out;
    float* out_item = out_user + (size_t)NU * C;

    // workspace: h (rc) | omean (rc) | cur (maxN ints) | csr (maxE ints)
    float* ws = (float*)d_ws;
    const size_t rc = (size_t)(NU + NI) * C;
    float* h_all     = ws;
    float* omean_all = h_all + rc;
    int*   cur       = (int*)(omean_all + rc);
    const int maxN   = (NU > NI) ? NU : NI;
    int*   csr       = cur + maxN;

    float* h_user = h_all;
    float* h_item = h_all + (size_t)NU * C;
    float* om_user = omean_all;
    float* om_item = omean_all + (size_t)NU * C;

    transform_kernel<<<(NU + 31) / 32, 256, 0, stream>>>(
        x_user, NU, W_nb, b_nb, W_self, b_self, h_user, out_user);
    transform_kernel<<<(NI + 31) / 32, 256, 0, stream>>>(
        x_item, NI, W_nb, b_nb, W_self, b_self, h_item, out_item);

    // direction A: user -> item
    zero_kernel<<<(NI + 255) / 256, 256, 0, stream>>>(cur, NI);
    hist_kernel<<<(E1 + 255) / 256, 256, 0, stream>>>(ei_u2i + E1, E1, cur);
    scan_kernel<<<1, 1024, 0, stream>>>(cur, NI);
    fill_kernel<<<(E1 + 255) / 256, 256, 0, stream>>>(ei_u2i, ei_u2i + E1, E1, cur, csr);
    attn_fused_kernel<<<(NI + ATN - 1) / ATN, 256, 0, stream>>>(
        h_user, csr, cur, out_item, Wip, bip, om_item, NI);

    // direction B: item -> user
    zero_kernel<<<(NU + 255) / 256, 256, 0, stream>>>(cur, NU);
    hist_kernel<<<(E2 + 255) / 256, 256, 0, stream>>>(ei_i2u + E2, E2, cur);
    scan_kernel<<<1, 1024, 0, stream>>>(cur, NU);
    fill_kernel<<<(E2 + 255) / 256, 256, 0, stream>>>(ei_i2u, ei_i2u + E2, E2, cur, csr);
    attn_fused_kernel<<<(NU + ATN - 1) / ATN, 256, 0, stream>>>(
        h_item, csr, cur, out_user, Wip, bip, om_user, NU);

    outproj_kernel<<<(NU + NI + 31) / 32, 256, 0, stream>>>(
        omean_all, Wop, bop, (float*)d_out, NU + NI);
}

// Round 7
// 1142.053 us; speedup vs baseline: 6.9387x; 1.5028x over previous
//
#include <hip/hip_runtime.h>
#include <hip/hip_bf16.h>

// ---------------------------------------------------------------------------
// AttentionHeteroConv. R7 = R6-base with:
//  (1) qkv GEMM on matrix cores: bf16 MFMA 16x16x32, fp32 accumulate.
//      A (32x128) and per-ks B (384x32) staged as bf16 in LDS, strides 136/40
//      bf16 (4-bank row rotation, conflict-free b128 fragment reads).
//  (2) tail overlay stride 388 (384 = 0 mod 32 banks was the real conflict
//      source) + float4 score reads.
// Transform / CSR / outproj / tail structure unchanged (R3-proven).
// ---------------------------------------------------------------------------

#define C 128
#define NHEAD 4
#define DH 32
#define QK_SCALE 0.17677669529663687f  // 1/sqrt(32)

typedef __attribute__((ext_vector_type(8))) short bf16x8;
typedef __attribute__((ext_vector_type(4))) short short4v;
typedef __attribute__((ext_vector_type(2))) short short2v;
typedef __attribute__((ext_vector_type(4))) float f32x4;

__device__ __forceinline__ short f2bf(float f) {
    unsigned u = __float_as_uint(f);
    unsigned r = u + 0x7FFFu + ((u >> 16) & 1u);   // round-to-nearest-even
    return (short)(r >> 16);
}

// ---------------------------------------------------------------------------
// K2: transform: h = x@Wnb^T + bnb ; self = x@Wself^T + bself  (R3 version)
// ---------------------------------------------------------------------------
__global__ __launch_bounds__(256) void transform_kernel(
    const float* __restrict__ x, int n_rows,
    const float* __restrict__ Wnb, const float* __restrict__ bnb,
    const float* __restrict__ Wself, const float* __restrict__ bself,
    float* __restrict__ h, float* __restrict__ selfout)
{
    __shared__ float At[32][C];
    const int tid = threadIdx.x;
    const int row0 = blockIdx.x * 32;

    for (int i = tid; i < 32 * 32; i += 256) {
        int r = i >> 5, c4 = i & 31;
        float4 v = make_float4(0.f, 0.f, 0.f, 0.f);
        if (row0 + r < n_rows) v = ((const float4*)x)[(size_t)(row0 + r) * 32 + c4];
        ((float4*)At[r])[c4] = v;
    }
    __syncthreads();

    const int col = tid & 127;
    const float* W = (tid < 128) ? Wnb : Wself;
    const float* bb = (tid < 128) ? bnb : bself;
    float* outp = (tid < 128) ? h : selfout;

    float acc[32];
#pragma unroll
    for (int r = 0; r < 32; r++) acc[r] = 0.f;

    const float4* w4 = (const float4*)(W + (size_t)col * C);
    for (int k4 = 0; k4 < 32; k4 += 4) {
        float4 w0 = w4[k4], w1 = w4[k4 + 1], w2 = w4[k4 + 2], w3 = w4[k4 + 3];
#pragma unroll
        for (int r = 0; r < 32; r++) {
            const float4* a4 = (const float4*)At[r];
            float4 a0 = a4[k4], a1 = a4[k4 + 1], a2 = a4[k4 + 2], a3 = a4[k4 + 3];
            acc[r] += a0.x * w0.x + a0.y * w0.y + a0.z * w0.z + a0.w * w0.w
                    + a1.x * w1.x + a1.y * w1.y + a1.z * w1.z + a1.w * w1.w
                    + a2.x * w2.x + a2.y * w2.y + a2.z * w2.z + a2.w * w2.w
                    + a3.x * w3.x + a3.y * w3.y + a3.z * w3.z + a3.w * w3.w;
        }
    }
    const float bias = bb[col];
#pragma unroll
    for (int r = 0; r < 32; r++) {
        int row = row0 + r;
        if (row < n_rows) outp[(size_t)row * C + col] = acc[r] + bias;
    }
}

// ---------------------------------------------------------------------------
// CSR build: zero + histogram + exclusive-scan (single block) + fill.
// ---------------------------------------------------------------------------
__global__ __launch_bounds__(256) void zero_kernel(int* __restrict__ p, int n)
{
    int i = blockIdx.x * 256 + threadIdx.x;
    if (i < n) p[i] = 0;
}

__global__ __launch_bounds__(256) void hist_kernel(
    const int* __restrict__ dst, int n, int* __restrict__ cur)
{
    int i = blockIdx.x * 256 + threadIdx.x;
    if (i < n) atomicAdd(&cur[dst[i]], 1);
}

__global__ __launch_bounds__(1024) void scan_kernel(int* __restrict__ cur, int n)
{
    __shared__ int wsum[16];
    __shared__ int carryS;
    const int tid = threadIdx.x, lane = tid & 63, wv = tid >> 6;
    if (tid == 0) carryS = 0;
    __syncthreads();
    for (int base = 0; base < n; base += 1024) {
        int i = base + tid;
        int v = (i < n) ? cur[i] : 0;
        int x = v;
#pragma unroll
        for (int d = 1; d < 64; d <<= 1) {
            int t = __shfl_up(x, d, 64);
            if (lane >= d) x += t;
        }
        if (lane == 63) wsum[wv] = x;
        int carry = carryS;
        __syncthreads();
        int wpre = 0;
#pragma unroll
        for (int w2 = 0; w2 < 16; w2++) wpre += (w2 < wv) ? wsum[w2] : 0;
        int excl = x - v + wpre + carry;
        if (i < n) cur[i] = excl;
        __syncthreads();
        if (tid == 0) {
            int t = 0;
#pragma unroll
            for (int w2 = 0; w2 < 16; w2++) t += wsum[w2];
            carryS = carry + t;
        }
        __syncthreads();
    }
}

__global__ __launch_bounds__(256) void fill_kernel(
    const int* __restrict__ src, const int* __restrict__ dst, int n,
    int* __restrict__ cur, int* __restrict__ csr)
{
    int i = blockIdx.x * 256 + threadIdx.x;
    if (i < n) {
        int p = atomicAdd(&cur[dst[i]], 1);
        csr[p] = src[i];
    }
}

// ---------------------------------------------------------------------------
// K4: fused gather-aggregate + bf16-MFMA qkv GEMM + attention, 8 nodes/block.
// LDS region R (floats, 66176 B), phase-sequenced:
//   GEMM:    A bf16 [32][136]  @byte 0      (row = node*4+s, col = k)
//            B bf16 [384][40]  @byte 8704   (row = n, col = k - ks*32)
//   overlay: qkv fp32 [40][388] @float 0    (rows node*5+s; q|k|v each 128)
// MFMA 16x16x32 bf16: wave w -> mhalf=w&1 (16 rows), nhalf=w>>1 (192 cols),
// 12 N-tiles x 4 K-steps = 48 MFMA/wave, acc 12 x f32x4.
// ---------------------------------------------------------------------------
#define ATN 8
#define RSZ 16544
#define QROW 388
#define BS_BYTE 8704

__global__ __launch_bounds__(256, 2) void attn_fused_kernel(
    const float* __restrict__ h_src, const int* __restrict__ csr,
    const int* __restrict__ cur, const float* __restrict__ selfF,
    const float* __restrict__ Wip, const float* __restrict__ bip,
    float* __restrict__ omean_g, int n_nodes)
{
    __shared__ float R[RSZ];
    __shared__ float omean[ATN][C];
    __shared__ float att[ATN][5][5];
    __shared__ float bipS[384];
    __shared__ float cinv[ATN];

    const int tid = threadIdx.x;
    const int lane = tid & 63;
    const int wv = tid >> 6;
    const int node0 = blockIdx.x * ATN;

    char* Abase = (char*)R;            // bf16 A tile
    char* Bbase = (char*)R + BS_BYTE;  // bf16 B tile

    // ---- P0a: stage bip + self rows (A row node*4+0, bf16) ----
    for (int i = tid; i < 384; i += 256) bipS[i] = bip[i];
    {
        int r = tid >> 5, c4 = tid & 31;
        int node = node0 + r;
        float4 v = make_float4(0.f, 0.f, 0.f, 0.f);
        if (node < n_nodes) v = ((const float4*)selfF)[(size_t)node * 32 + c4];
        short4v b;
        b.x = f2bf(v.x); b.y = f2bf(v.y); b.z = f2bf(v.z); b.w = f2bf(v.w);
        *(short4v*)(Abase + (r * 4) * 272 + c4 * 8) = b;
    }

    // ---- P0b: gather max/min/sum -> A rows node*4+{1,2,3} (bf16) ----
    const float2* h2 = (const float2*)h_src;
#pragma unroll
    for (int half = 0; half < 2; half++) {
        int nl = wv * 2 + half;
        int node = node0 + nl;
        float2 vs = make_float2(0.f, 0.f);
        float2 vmx = make_float2(-3.4e38f, -3.4e38f);
        float2 vmn = make_float2(3.4e38f, 3.4e38f);
        int deg = 0;
        if (node < n_nodes) {
            int start = (node == 0) ? 0 : cur[node - 1];
            int end = cur[node];
            deg = end - start;
            int e = start;
            for (; e + 4 <= end; e += 4) {
                int s0 = csr[e], s1 = csr[e + 1], s2 = csr[e + 2], s3 = csr[e + 3];
                float2 v0 = h2[(size_t)s0 * 64 + lane];
                float2 v1 = h2[(size_t)s1 * 64 + lane];
                float2 v2 = h2[(size_t)s2 * 64 + lane];
                float2 v3 = h2[(size_t)s3 * 64 + lane];
                vs.x += v0.x + v1.x + v2.x + v3.x;
                vs.y += v0.y + v1.y + v2.y + v3.y;
                vmx.x = fmaxf(fmaxf(vmx.x, v0.x), fmaxf(v1.x, fmaxf(v2.x, v3.x)));
                vmx.y = fmaxf(fmaxf(vmx.y, v0.y), fmaxf(v1.y, fmaxf(v2.y, v3.y)));
                vmn.x = fminf(fminf(vmn.x, v0.x), fminf(v1.x, fminf(v2.x, v3.x)));
                vmn.y = fminf(fminf(vmn.y, v0.y), fminf(v1.y, fminf(v2.y, v3.y)));
            }
            for (; e < end; e++) {
                int s0 = csr[e];
                float2 v0 = h2[(size_t)s0 * 64 + lane];
                vs.x += v0.x; vs.y += v0.y;
                vmx.x = fmaxf(vmx.x, v0.x); vmx.y = fmaxf(vmx.y, v0.y);
                vmn.x = fminf(vmn.x, v0.x); vmn.y = fminf(vmn.y, v0.y);
            }
        }
        if (deg == 0) {
            vmx = make_float2(0.f, 0.f);
            vmn = make_float2(0.f, 0.f);
        }
        short2v p;
        p.x = f2bf(vmx.x); p.y = f2bf(vmx.y);
        *(short2v*)(Abase + (nl * 4 + 1) * 272 + lane * 4) = p;
        p.x = f2bf(vmn.x); p.y = f2bf(vmn.y);
        *(short2v*)(Abase + (nl * 4 + 2) * 272 + lane * 4) = p;
        p.x = f2bf(vs.x); p.y = f2bf(vs.y);
        *(short2v*)(Abase + (nl * 4 + 3) * 272 + lane * 4) = p;
        if (lane == 0) cinv[nl] = 1.f / (float)max(deg, 1);
    }

    // ---- P1: MFMA GEMM qkv = A @ Wip^T  (M=32, N=384, K=128) ----
    const int mhalf = wv & 1;
    const int nhalf = wv >> 1;
    const int quad = (tid >> 4) & 3;
    const int col16 = tid & 15;

    f32x4 acc[12];
#pragma unroll
    for (int t = 0; t < 12; t++) acc[t] = (f32x4){0.f, 0.f, 0.f, 0.f};

    const float4* Wip4 = (const float4*)Wip;
    const char* bp = Bbase + (nhalf * 192 + col16) * 80 + quad * 16;

    for (int ks = 0; ks < 4; ks++) {
        __syncthreads();
        // stage B chunk: Wip[n][ks*32 .. +31] -> bf16 [384][40]
        for (int i = 0; i < 12; i++) {
            int id = tid + i * 256;          // 3072 = 384 n x 8 q
            int n = id >> 3, q = id & 7;
            float4 w = Wip4[(size_t)n * 32 + ks * 8 + q];
            short4v b;
            b.x = f2bf(w.x); b.y = f2bf(w.y); b.z = f2bf(w.z); b.w = f2bf(w.w);
            *(short4v*)(Bbase + n * 80 + q * 8) = b;
        }
        __syncthreads();
        bf16x8 af = *(const bf16x8*)(Abase + (mhalf * 16 + col16) * 272
                                     + ks * 64 + quad * 16);
#pragma unroll
        for (int t = 0; t < 12; t++) {
            bf16x8 bf = *(const bf16x8*)(bp + t * 1280);
            acc[t] = __builtin_amdgcn_mfma_f32_16x16x32_bf16(af, bf, acc[t], 0, 0, 0);
        }
    }

    // ---- P2: C-frags (+bias) -> qkv overlay rows node*5+s ----
    __syncthreads();
#pragma unroll
    for (int t = 0; t < 12; t++) {
        int col = nhalf * 192 + t * 16 + col16;
        float bias = bipS[col];
#pragma unroll
        for (int reg = 0; reg < 4; reg++) {
            int m = mhalf * 16 + quad * 4 + reg;
            int node = m >> 2, s = m & 3;
            R[(node * 5 + s) * QROW + col] = acc[t][reg] + bias;
        }
    }
    __syncthreads();

    // ---- P3: derive mean rows: (qkv_sum - b)*cinv + b ----
    for (int i = 0; i < 12; i++) {
        int id = tid + i * 256;              // 3072 = 8 x 384
        int n = id / 384, c = id - n * 384;
        float b = bipS[c];
        R[(n * 5 + 4) * QROW + c] = (R[(n * 5 + 3) * QROW + c] - b) * cinv[n] + b;
    }
    __syncthreads();

    // ---- P4: per-head scores/softmax/PV ----
    for (int h = 0; h < NHEAD; h++) {
        if (tid < ATN * 25) {
            int n = tid / 25, ij = tid - n * 25, i = ij / 5, j = ij - (ij / 5) * 5;
            const float4* qr = (const float4*)&R[(n * 5 + i) * QROW + h * DH];
            const float4* kr = (const float4*)&R[(n * 5 + j) * QROW + C + h * DH];
            float s = 0.f;
#pragma unroll
            for (int d4 = 0; d4 < 8; d4++) {
                float4 q = qr[d4], k = kr[d4];
                s += q.x * k.x + q.y * k.y + q.z * k.z + q.w * k.w;
            }
            att[n][i][j] = s * QK_SCALE;
        }
        __syncthreads();
        if (tid < ATN * 5) {
            int n = tid / 5, i = tid - n * 5;
            float m = att[n][i][0];
#pragma unroll
            for (int j = 1; j < 5; j++) m = fmaxf(m, att[n][i][j]);
            float e[5], l = 0.f;
#pragma unroll
            for (int j = 0; j < 5; j++) { e[j] = __expf(att[n][i][j] - m); l += e[j]; }
            float inv = 0.2f / l;
#pragma unroll
            for (int j = 0; j < 5; j++) att[n][i][j] = e[j] * inv;
        }
        __syncthreads();
        {
            int n = tid >> 5, d = tid & 31;
            float a2 = 0.f;
#pragma unroll
            for (int j = 0; j < 5; j++) {
                float wj = att[n][0][j] + att[n][1][j] + att[n][2][j]
                         + att[n][3][j] + att[n][4][j];
                a2 += wj * R[(n * 5 + j) * QROW + 2 * C + h * DH + d];
            }
            omean[n][h * DH + d] = a2;
        }
        __syncthreads();
    }

    // ---- P5: omean -> global ----
#pragma unroll
    for (int i = 0; i < 4; i++) {
        int id = tid + i * 256;
        int n = id >> 7, c = id & 127;
        int node = node0 + n;
        if (node < n_nodes) omean_g[(size_t)node * C + c] = omean[n][c];
    }
}

// ---------------------------------------------------------------------------
// K5: out = self(d_out) + omean @ Wop^T + bop.  (R3 version)
// ---------------------------------------------------------------------------
__global__ __launch_bounds__(256, 4) void outproj_kernel(
    const float* __restrict__ omean_g, const float* __restrict__ Wop,
    const float* __restrict__ bop, float* __restrict__ out, int M)
{
    __shared__ float As[32 * 132];
    __shared__ float Bs[32 * 132];
    __shared__ float bopS[C];
    const int tid = threadIdx.x;
    const int m0 = blockIdx.x * 32;

    if (tid < C) bopS[tid] = bop[tid];
#pragma unroll
    for (int i = 0; i < 4; i++) {
        int id = tid + i * 256;
        int r = id >> 5, c4 = id & 31;
        float4 v = make_float4(0.f, 0.f, 0.f, 0.f);
        int m = m0 + r;
        if (m < M) v = ((const float4*)omean_g)[(size_t)m * 32 + c4];
        *(float4*)&As[r * 132 + c4 * 4] = v;
    }

    const int tn = tid & 31;
    const int tm = tid >> 5;
    float acc[4][4];
#pragma unroll
    for (int m = 0; m < 4; m++)
#pragma unroll
        for (int n = 0; n < 4; n++) acc[m][n] = 0.f;

    for (int ks = 0; ks < 4; ks++) {
        __syncthreads();
        for (int i = 0; i < 4; i++) {
            int id = tid + i * 256;          // 1024 = 128 n x 8 q
            int n = id >> 3, q = id & 7;
            float4 w = ((const float4*)Wop)[(size_t)n * 32 + ks * 8 + q];
            Bs[(q * 4 + 0) * 132 + n] = w.x;
            Bs[(q * 4 + 1) * 132 + n] = w.y;
            Bs[(q * 4 + 2) * 132 + n] = w.z;
            Bs[(q * 4 + 3) * 132 + n] = w.w;
        }
        __syncthreads();
#pragma unroll 4
        for (int k4 = 0; k4 < 8; k4++) {
            float4 a[4];
#pragma unroll
            for (int m = 0; m < 4; m++)
                a[m] = *(const float4*)&As[(tm * 4 + m) * 132 + ks * 32 + k4 * 4];
#pragma unroll
            for (int kk = 0; kk < 4; kk++) {
                float4 b = *(const float4*)&Bs[(k4 * 4 + kk) * 132 + tn * 4];
#pragma unroll
                for (int m = 0; m < 4; m++) {
                    float av = ((const float*)&a[m])[kk];
                    acc[m][0] += av * b.x; acc[m][1] += av * b.y;
                    acc[m][2] += av * b.z; acc[m][3] += av * b.w;
                }
            }
        }
    }

#pragma unroll
    for (int m = 0; m < 4; m++) {
        int row = m0 + tm * 4 + m;
        if (row < M) {
            float4* o = (float4*)&out[(size_t)row * C + tn * 4];
            float4 r = *o;
            r.x += acc[m][0] + bopS[tn * 4 + 0];
            r.y += acc[m][1] + bopS[tn * 4 + 1];
            r.z += acc[m][2] + bopS[tn * 4 + 2];
            r.w += acc[m][3] + bopS[tn * 4 + 3];
            *o = r;
        }
    }
}

// ---------------------------------------------------------------------------
extern "C" void kernel_launch(void* const* d_in, const int* in_sizes, int n_in,
                              void* d_out, int out_size, void* d_ws, size_t ws_size,
                              hipStream_t stream) {
    const float* x_user = (const float*)d_in[0];
    const float* x_item = (const float*)d_in[1];
    const int*   ei_u2i = (const int*)d_in[2];
    const int*   ei_i2u = (const int*)d_in[3];
    const float* W_nb   = (const float*)d_in[4];
    const float* b_nb   = (const float*)d_in[5];
    const float* W_self = (const float*)d_in[6];
    const float* b_self = (const float*)d_in[7];
    const float* Wip    = (const float*)d_in[8];
    const float* bip    = (const float*)d_in[9];
    const float* Wop    = (const float*)d_in[10];
    const float* bop    = (const float*)d_in[11];

    const int NU = in_sizes[0] / C;
    const int NI = in_sizes[1] / C;
    const int E1 = in_sizes[2] / 2;
    const int E2 = in_sizes[3] / 2;

    float* out_user = (float*)d_out;
    float* out_item = out_user + (size_t)NU * C;

    // workspace: h (rc) | omean (rc) | cur (maxN ints) | csr (maxE ints)
    float* ws = (float*)d_ws;
    const size_t rc = (size_t)(NU + NI) * C;
    float* h_all     = ws;
    float* omean_all = h_all + rc;
    int*   cur       = (int*)(omean_all + rc);
    const int maxN   = (NU > NI) ? NU : NI;
    int*   csr       = cur + maxN;

    float* h_user = h_all;
    float* h_item = h_all + (size_t)NU * C;
    float* om_user = omean_all;
    float* om_item = omean_all + (size_t)NU * C;

    transform_kernel<<<(NU + 31) / 32, 256, 0, stream>>>(
        x_user, NU, W_nb, b_nb, W_self, b_self, h_user, out_user);
    transform_kernel<<<(NI + 31) / 32, 256, 0, stream>>>(
        x_item, NI, W_nb, b_nb, W_self, b_self, h_item, out_item);

    // direction A: user -> item
    zero_kernel<<<(NI + 255) / 256, 256, 0, stream>>>(cur, NI);
    hist_kernel<<<(E1 + 255) / 256, 256, 0, stream>>>(ei_u2i + E1, E1, cur);
    scan_kernel<<<1, 1024, 0, stream>>>(cur, NI);
    fill_kernel<<<(E1 + 255) / 256, 256, 0, stream>>>(ei_u2i, ei_u2i + E1, E1, cur, csr);
    attn_fused_kernel<<<(NI + ATN - 1) / ATN, 256, 0, stream>>>(
        h_user, csr, cur, out_item, Wip, bip, om_item, NI);

    // direction B: item -> user
    zero_kernel<<<(NU + 255) / 256, 256, 0, stream>>>(cur, NU);
    hist_kernel<<<(E2 + 255) / 256, 256, 0, stream>>>(ei_i2u + E2, E2, cur);
    scan_kernel<<<1, 1024, 0, stream>>>(cur, NU);
    fill_kernel<<<(E2 + 255) / 256, 256, 0, stream>>>(ei_i2u, ei_i2u + E2, E2, cur, csr);
    attn_fused_kernel<<<(NU + ATN - 1) / ATN, 256, 0, stream>>>(
        h_item, csr, cur, out_user, Wip, bip, om_user, NU);

    outproj_kernel<<<(NU + NI + 31) / 32, 256, 0, stream>>>(
        omean_all, Wop, bop, (float*)d_out, NU + NI);
}